// Round 2
// baseline (121.508 us; speedup 1.0000x reference)
//
#include <hip/hip_runtime.h>
#include <hip/hip_bf16.h>

#define B_TOT   4096
#define T_STEPS 256
#define IN_D    28
#define HID     128
#define OUT_D   784
#define BM      16

typedef __bf16 bf16x8 __attribute__((ext_vector_type(8)));
typedef float  f32x4  __attribute__((ext_vector_type(4)));
typedef float  f32x2  __attribute__((ext_vector_type(2)));

__device__ __forceinline__ float bf2f(__bf16 b) {
    unsigned short s = __builtin_bit_cast(unsigned short, b);
    unsigned int u = ((unsigned int)s) << 16;
    return __builtin_bit_cast(float, u);
}
__device__ __forceinline__ unsigned short f2bfbits(float f) {
    unsigned int u = __builtin_bit_cast(unsigned int, f);
    u += 0x7fffu + ((u >> 16) & 1u);   // RNE (finite values)
    return (unsigned short)(u >> 16);
}
__device__ __forceinline__ __bf16 f2bf(float f) {
    return __builtin_bit_cast(__bf16, f2bfbits(f));
}

// H LDS layout: [16 rows][128 bf16] = 256 B/row, XOR-swizzled so the
// stride-256B fragment reads spread across banks (2-way = free, m136).
__device__ __forceinline__ int hswz(int row, int byteInRow) {
    return row * 256 + (byteInRow ^ ((row & 7) << 4));
}

__global__ __launch_bounds__(256) void rnn_fused(
    const float* __restrict__ x,     // [B,T,IN] f32
    const float* __restrict__ h0,    // [B,HID] f32
    const float* __restrict__ W_ih,  // [HID,IN] f32
    const float* __restrict__ b_ih,  // [HID] f32
    const float* __restrict__ W_hh,  // [HID,HID] f32
    const float* __restrict__ b_hh,  // [HID] f32
    const float* __restrict__ W_ho,  // [OUT_D,HID] f32
    const float* __restrict__ b_ho,  // [OUT_D] f32
    float* __restrict__ out)         // [B*OUT_D] f32, then [B*HID] f32
{
    __shared__ __align__(16) unsigned char Hb[2][BM * 256]; // h (bf16) double buffer
    __shared__ __align__(16) unsigned char Xb[2][BM * 80];  // x_t (bf16) double buffer, [16][40]

    const int tid  = threadIdx.x;
    const int lane = tid & 63;
    const int wv   = tid >> 6;       // wave 0..3
    const int ln15 = lane & 15;
    const int lg   = lane >> 4;      // k-group 0..3
    const int b0   = blockIdx.x * BM;

    // ---- B-operand weight fragments (convert f32 -> bf16), register-resident.
    // B-frag elem e of lane l = W^T[k][n] = W[n][k], n = ntile + (l&15),
    // k = kc*32 + (l>>4)*8 + e  -> 8 consecutive k = contiguous 32B in f32 W.
    const int nt0 = wv * 32;         // this wave owns hidden cols [nt0, nt0+32)
    bf16x8 bw[2][4];
    #pragma unroll
    for (int ti = 0; ti < 2; ++ti) {
        int n = nt0 + ti * 16 + ln15;
        #pragma unroll
        for (int kc = 0; kc < 4; ++kc) {
            const float* p = W_hh + n * HID + kc * 32 + lg * 8;
            bf16x8 v;
            #pragma unroll
            for (int e = 0; e < 8; ++e) v[e] = f2bf(p[e]);
            bw[ti][kc] = v;
        }
    }
    const __bf16 bzero = __builtin_bit_cast(__bf16, (unsigned short)0);
    bf16x8 bxf[2];
    #pragma unroll
    for (int ti = 0; ti < 2; ++ti) {
        int n = nt0 + ti * 16 + ln15;
        bf16x8 v;
        #pragma unroll
        for (int e = 0; e < 8; ++e) {
            int k = lg * 8 + e;
            v[e] = (k < IN_D) ? f2bf(W_ih[n * IN_D + k]) : bzero;  // zero-pad K 28->32
        }
        bxf[ti] = v;
    }
    float bias2[2];
    #pragma unroll
    for (int ti = 0; ti < 2; ++ti) {
        int n = nt0 + ti * 16 + ln15;
        bias2[ti] = b_ih[n] + b_hh[n];
    }

    // ---- stage initial hidden into Hb[0] (f32 -> bf16)
    {
        int row = tid >> 4, cg = tid & 15;
        const float* p = h0 + (size_t)(b0 + row) * HID + cg * 8;
        bf16x8 hv;
        #pragma unroll
        for (int e = 0; e < 8; ++e) hv[e] = f2bf(p[e]);
        *(bf16x8*)(&Hb[0][hswz(row, cg * 16)]) = hv;
    }
    // ---- zero the k=28..31 pad of both X buffers (staging never touches it)
    if (tid < 64) {
        int bufi = tid >> 5, idx = tid & 31, row = idx >> 1, half = idx & 1;
        *(unsigned int*)(&Xb[bufi][row * 80 + 56 + half * 4]) = 0u;
    }
    // ---- stage x_0: 16 rows x 14 float-pairs, convert to packed bf16x2
    const int xrow = tid / 14, xpair = tid % 14;
    if (tid < 224) {
        f32x2 v = *(const f32x2*)(x + ((size_t)(b0 + xrow) * T_STEPS) * IN_D + xpair * 2);
        unsigned int pk = ((unsigned int)f2bfbits(v[1]) << 16) | f2bfbits(v[0]);
        *(unsigned int*)(&Xb[0][xrow * 80 + xpair * 4]) = pk;
    }
    __syncthreads();

    // ================= recurrence: 256 steps, 1 barrier/step =================
    for (int t = 0; t < T_STEPS; ++t) {
        const int rb = t & 1;
        // prefetch next x_t to registers (write to LDS after compute)
        f32x2 xv = {0.f, 0.f};
        const bool pf = (t + 1 < T_STEPS) && (tid < 224);
        if (pf) xv = *(const f32x2*)(x + ((size_t)(b0 + xrow) * T_STEPS + (t + 1)) * IN_D + xpair * 2);

        // A fragments: row = lane&15, k = kc*32 + (lane>>4)*8 + e
        bf16x8 ax  = *(const bf16x8*)(&Xb[rb][ln15 * 80 + lg * 16]);
        bf16x8 ah0 = *(const bf16x8*)(&Hb[rb][hswz(ln15,   0 + lg * 16)]);
        bf16x8 ah1 = *(const bf16x8*)(&Hb[rb][hswz(ln15,  64 + lg * 16)]);
        bf16x8 ah2 = *(const bf16x8*)(&Hb[rb][hswz(ln15, 128 + lg * 16)]);
        bf16x8 ah3 = *(const bf16x8*)(&Hb[rb][hswz(ln15, 192 + lg * 16)]);

        f32x4 acc0 = {bias2[0], bias2[0], bias2[0], bias2[0]};
        f32x4 acc1 = {bias2[1], bias2[1], bias2[1], bias2[1]};
        acc0 = __builtin_amdgcn_mfma_f32_16x16x32_bf16(ax,  bxf[0],   acc0, 0, 0, 0);
        acc1 = __builtin_amdgcn_mfma_f32_16x16x32_bf16(ax,  bxf[1],   acc1, 0, 0, 0);
        acc0 = __builtin_amdgcn_mfma_f32_16x16x32_bf16(ah0, bw[0][0], acc0, 0, 0, 0);
        acc1 = __builtin_amdgcn_mfma_f32_16x16x32_bf16(ah0, bw[1][0], acc1, 0, 0, 0);
        acc0 = __builtin_amdgcn_mfma_f32_16x16x32_bf16(ah1, bw[0][1], acc0, 0, 0, 0);
        acc1 = __builtin_amdgcn_mfma_f32_16x16x32_bf16(ah1, bw[1][1], acc1, 0, 0, 0);
        acc0 = __builtin_amdgcn_mfma_f32_16x16x32_bf16(ah2, bw[0][2], acc0, 0, 0, 0);
        acc1 = __builtin_amdgcn_mfma_f32_16x16x32_bf16(ah2, bw[1][2], acc1, 0, 0, 0);
        acc0 = __builtin_amdgcn_mfma_f32_16x16x32_bf16(ah3, bw[0][3], acc0, 0, 0, 0);
        acc1 = __builtin_amdgcn_mfma_f32_16x16x32_bf16(ah3, bw[1][3], acc1, 0, 0, 0);

        // ReLU + bf16 + write h_new into the other buffer.
        // D layout (m89-verified): col = lane&15, row = (lane>>4)*4 + r
        #pragma unroll
        for (int ti = 0; ti < 2; ++ti) {
            f32x4 a = ti ? acc1 : acc0;
            #pragma unroll
            for (int r = 0; r < 4; ++r) {
                float v = a[r];
                v = v > 0.f ? v : 0.f;
                int row  = lg * 4 + r;
                int colb = (nt0 + ti * 16 + ln15) * 2;
                *(__bf16*)(&Hb[rb ^ 1][hswz(row, colb)]) = f2bf(v);
            }
        }
        if (pf) {
            unsigned int pk = ((unsigned int)f2bfbits(xv[1]) << 16) | f2bfbits(xv[0]);
            *(unsigned int*)(&Xb[rb ^ 1][xrow * 80 + xpair * 4]) = pk;
        }
        __syncthreads();
    }
    // after t=255 (rb=1) the final h sits in Hb[0]

    // ================= epilogue =================
    // h_final -> d_out second segment (f32)
    {
        int row = tid >> 4, cg = tid & 15;
        bf16x8 hv = *(const bf16x8*)(&Hb[0][hswz(row, cg * 16)]);
        float* po = out + (size_t)B_TOT * OUT_D + (size_t)(b0 + row) * HID + cg * 8;
        #pragma unroll
        for (int e = 0; e < 8; ++e) po[e] = bf2f(hv[e]);
    }
    // projection: out[b][o] = h_final[b] . W_ho[o] + b_ho[o],  49 N-tiles of 16
    bf16x8 af[4];
    #pragma unroll
    for (int kc = 0; kc < 4; ++kc)
        af[kc] = *(const bf16x8*)(&Hb[0][hswz(ln15, kc * 64 + lg * 16)]);

    for (int nt = wv; nt < 49; nt += 4) {
        int n = nt * 16 + ln15;
        float bo = b_ho[n];
        f32x4 acc = {bo, bo, bo, bo};
        #pragma unroll
        for (int kc = 0; kc < 4; ++kc) {
            const float* p = W_ho + n * HID + kc * 32 + lg * 8;
            bf16x8 bfrag;
            #pragma unroll
            for (int e = 0; e < 8; ++e) bfrag[e] = f2bf(p[e]);
            acc = __builtin_amdgcn_mfma_f32_16x16x32_bf16(af[kc], bfrag, acc, 0, 0, 0);
        }
        #pragma unroll
        for (int r = 0; r < 4; ++r) {
            int row = lg * 4 + r;
            out[(size_t)(b0 + row) * OUT_D + n] = acc[r];
        }
    }
}

extern "C" void kernel_launch(void* const* d_in, const int* in_sizes, int n_in,
                              void* d_out, int out_size, void* d_ws, size_t ws_size,
                              hipStream_t stream) {
    const float* x    = (const float*)d_in[0];
    const float* h0   = (const float*)d_in[1];
    const float* W_ih = (const float*)d_in[2];
    const float* b_ih = (const float*)d_in[3];
    const float* W_hh = (const float*)d_in[4];
    const float* b_hh = (const float*)d_in[5];
    const float* W_ho = (const float*)d_in[6];
    const float* b_ho = (const float*)d_in[7];
    rnn_fused<<<B_TOT / BM, 256, 0, stream>>>(x, h0, W_ih, b_ih, W_hh, b_hh,
                                              W_ho, b_ho, (float*)d_out);
}

// Round 3
// 107.403 us; speedup vs baseline: 1.1313x; 1.1313x over previous
//
#include <hip/hip_runtime.h>
#include <hip/hip_bf16.h>

#define B_TOT   4096
#define T_STEPS 256
#define IN_D    28
#define HID     128
#define OUT_D   784
#define BM      16

typedef __bf16 bf16x8 __attribute__((ext_vector_type(8)));
typedef float  f32x4  __attribute__((ext_vector_type(4)));
typedef float  f32x2  __attribute__((ext_vector_type(2)));

__device__ __forceinline__ float bf2f(__bf16 b) {
    unsigned short s = __builtin_bit_cast(unsigned short, b);
    unsigned int u = ((unsigned int)s) << 16;
    return __builtin_bit_cast(float, u);
}
__device__ __forceinline__ unsigned short f2bfbits(float f) {
    unsigned int u = __builtin_bit_cast(unsigned int, f);
    u += 0x7fffu + ((u >> 16) & 1u);   // RNE (finite values)
    return (unsigned short)(u >> 16);
}
__device__ __forceinline__ __bf16 f2bf(float f) {
    return __builtin_bit_cast(__bf16, f2bfbits(f));
}

// H LDS layout: [16 rows][128 bf16] = 256 B/row, XOR-swizzled so the
// stride-256B fragment reads spread across banks (2-way = free, m136).
__device__ __forceinline__ int hswz(int row, int byteInRow) {
    return row * 256 + (byteInRow ^ ((row & 7) << 4));
}

__global__ __launch_bounds__(256) void rnn_fused(
    const float* __restrict__ x,     // [B,T,IN] f32
    const float* __restrict__ h0,    // [B,HID] f32
    const float* __restrict__ W_ih,  // [HID,IN] f32
    const float* __restrict__ b_ih,  // [HID] f32
    const float* __restrict__ W_hh,  // [HID,HID] f32
    const float* __restrict__ b_hh,  // [HID] f32
    const float* __restrict__ W_ho,  // [OUT_D,HID] f32
    const float* __restrict__ b_ho,  // [OUT_D] f32
    float* __restrict__ out)         // [B*OUT_D] f32, then [B*HID] f32
{
    __shared__ __align__(16) unsigned char Hb[2][BM * 256]; // h (bf16) double buffer
    __shared__ __align__(16) unsigned char Xb[2][BM * 80];  // x_t (bf16) double buffer, [16][40]

    const int tid  = threadIdx.x;
    const int lane = tid & 63;
    const int wv   = tid >> 6;       // wave 0..3
    const int ln15 = lane & 15;
    const int lg   = lane >> 4;      // k-group 0..3
    const int b0   = blockIdx.x * BM;

    // ---- B-operand weight fragments (f32 -> bf16), register-resident.
    const int nt0 = wv * 32;         // this wave owns hidden cols [nt0, nt0+32)
    bf16x8 bw[2][4];
    #pragma unroll
    for (int ti = 0; ti < 2; ++ti) {
        int n = nt0 + ti * 16 + ln15;
        #pragma unroll
        for (int kc = 0; kc < 4; ++kc) {
            const float* p = W_hh + n * HID + kc * 32 + lg * 8;
            bf16x8 v;
            #pragma unroll
            for (int e = 0; e < 8; ++e) v[e] = f2bf(p[e]);
            bw[ti][kc] = v;
        }
    }
    const __bf16 bzero = __builtin_bit_cast(__bf16, (unsigned short)0);
    bf16x8 bxf[2];
    #pragma unroll
    for (int ti = 0; ti < 2; ++ti) {
        int n = nt0 + ti * 16 + ln15;
        bf16x8 v;
        #pragma unroll
        for (int e = 0; e < 8; ++e) {
            int k = lg * 8 + e;
            v[e] = (k < IN_D) ? f2bf(W_ih[n * IN_D + k]) : bzero;  // zero-pad K 28->32
        }
        bxf[ti] = v;
    }
    float bias2[2];
    #pragma unroll
    for (int ti = 0; ti < 2; ++ti) {
        int n = nt0 + ti * 16 + ln15;
        bias2[ti] = b_ih[n] + b_hh[n];
    }

    // ---- stage initial hidden into Hb[0] (f32 -> bf16)
    {
        int row = tid >> 4, cg = tid & 15;
        const float* p = h0 + (size_t)(b0 + row) * HID + cg * 8;
        bf16x8 hv;
        #pragma unroll
        for (int e = 0; e < 8; ++e) hv[e] = f2bf(p[e]);
        *(bf16x8*)(&Hb[0][hswz(row, cg * 16)]) = hv;
    }
    // ---- zero the k=28..31 pad of both X buffers (staging never touches it)
    if (tid < 64) {
        int bufi = tid >> 5, idx = tid & 31, row = idx >> 1, half = idx & 1;
        *(unsigned int*)(&Xb[bufi][row * 80 + 56 + half * 4]) = 0u;
    }
    // ---- stage x_0: 16 rows x 14 float-pairs, convert to packed bf16x2
    const int xrow = tid / 14, xpair = tid % 14;
    const bool xthr = (tid < 224);
    const float* xbase = x + (size_t)(b0 + xrow) * T_STEPS * IN_D + xpair * 2;
    if (xthr) {
        f32x2 v = *(const f32x2*)(xbase + 0 * IN_D);
        unsigned int pk = ((unsigned int)f2bfbits(v[1]) << 16) | f2bfbits(v[0]);
        *(unsigned int*)(&Xb[0][xrow * 80 + xpair * 4]) = pk;
    }
    // ---- deep x prefetch ring: p0..p3 hold x_{t+1}..x_{t+4}
    f32x2 p0 = {0.f, 0.f}, p1 = p0, p2 = p0, p3 = p0;
    if (xthr) {
        p0 = *(const f32x2*)(xbase + 1 * IN_D);
        p1 = *(const f32x2*)(xbase + 2 * IN_D);
        p2 = *(const f32x2*)(xbase + 3 * IN_D);
        p3 = *(const f32x2*)(xbase + 4 * IN_D);
    }
    __syncthreads();

    // ================= recurrence: 256 steps, 1 barrier/step =================
    // STEP(t): consume Xb/Hb[t&1]; write h_{t+1} and x_{t+1} into buffers [t&1 ^1];
    // P holds x_{t+1} (loaded 4 steps ago); reload P = x_{t+5}.
#define STEP(T, P)                                                              \
    {                                                                           \
        const int rb = (T) & 1;                                                 \
        bf16x8 ax  = *(const bf16x8*)(&Xb[rb][ln15 * 80 + lg * 16]);            \
        bf16x8 ah0 = *(const bf16x8*)(&Hb[rb][hswz(ln15,   0 + lg * 16)]);      \
        bf16x8 ah1 = *(const bf16x8*)(&Hb[rb][hswz(ln15,  64 + lg * 16)]);      \
        bf16x8 ah2 = *(const bf16x8*)(&Hb[rb][hswz(ln15, 128 + lg * 16)]);      \
        bf16x8 ah3 = *(const bf16x8*)(&Hb[rb][hswz(ln15, 192 + lg * 16)]);      \
        if (((T) + 1 < T_STEPS) && xthr) {                                      \
            unsigned int pk = ((unsigned int)f2bfbits(P[1]) << 16) | f2bfbits(P[0]); \
            *(unsigned int*)(&Xb[rb ^ 1][xrow * 80 + xpair * 4]) = pk;          \
        }                                                                       \
        if (((T) + 5 < T_STEPS) && xthr)                                        \
            P = *(const f32x2*)(xbase + (size_t)((T) + 5) * IN_D);              \
        f32x4 acc0 = {bias2[0], bias2[0], bias2[0], bias2[0]};                  \
        f32x4 acc1 = {bias2[1], bias2[1], bias2[1], bias2[1]};                  \
        acc0 = __builtin_amdgcn_mfma_f32_16x16x32_bf16(ax,  bxf[0],   acc0, 0, 0, 0); \
        acc1 = __builtin_amdgcn_mfma_f32_16x16x32_bf16(ax,  bxf[1],   acc1, 0, 0, 0); \
        acc0 = __builtin_amdgcn_mfma_f32_16x16x32_bf16(ah0, bw[0][0], acc0, 0, 0, 0); \
        acc1 = __builtin_amdgcn_mfma_f32_16x16x32_bf16(ah0, bw[1][0], acc1, 0, 0, 0); \
        acc0 = __builtin_amdgcn_mfma_f32_16x16x32_bf16(ah1, bw[0][1], acc0, 0, 0, 0); \
        acc1 = __builtin_amdgcn_mfma_f32_16x16x32_bf16(ah1, bw[1][1], acc1, 0, 0, 0); \
        acc0 = __builtin_amdgcn_mfma_f32_16x16x32_bf16(ah2, bw[0][2], acc0, 0, 0, 0); \
        acc1 = __builtin_amdgcn_mfma_f32_16x16x32_bf16(ah2, bw[1][2], acc1, 0, 0, 0); \
        acc0 = __builtin_amdgcn_mfma_f32_16x16x32_bf16(ah3, bw[0][3], acc0, 0, 0, 0); \
        acc1 = __builtin_amdgcn_mfma_f32_16x16x32_bf16(ah3, bw[1][3], acc1, 0, 0, 0); \
        _Pragma("unroll")                                                       \
        for (int ti = 0; ti < 2; ++ti) {                                        \
            f32x4 a = ti ? acc1 : acc0;                                         \
            _Pragma("unroll")                                                   \
            for (int r = 0; r < 4; ++r) {                                       \
                float v = a[r];                                                 \
                v = v > 0.f ? v : 0.f;                                          \
                int row  = lg * 4 + r;                                          \
                int colb = (nt0 + ti * 16 + ln15) * 2;                          \
                *(__bf16*)(&Hb[rb ^ 1][hswz(row, colb)]) = f2bf(v);             \
            }                                                                   \
        }                                                                       \
        __syncthreads();                                                        \
    }

    for (int t = 0; t < T_STEPS; t += 4) {
        STEP(t + 0, p0)
        STEP(t + 1, p1)
        STEP(t + 2, p2)
        STEP(t + 3, p3)
    }
#undef STEP
    // after t=255 (rb=1) the final h sits in Hb[0]

    // ================= epilogue =================
    // h_final -> d_out second segment (f32)
    {
        int row = tid >> 4, cg = tid & 15;
        bf16x8 hv = *(const bf16x8*)(&Hb[0][hswz(row, cg * 16)]);
        float* po = out + (size_t)B_TOT * OUT_D + (size_t)(b0 + row) * HID + cg * 8;
        #pragma unroll
        for (int e = 0; e < 8; ++e) po[e] = bf2f(hv[e]);
    }
    // projection: out[b][o] = h_final[b] . W_ho[o] + b_ho[o],  49 N-tiles of 16
    bf16x8 af[4];
    #pragma unroll
    for (int kc = 0; kc < 4; ++kc)
        af[kc] = *(const bf16x8*)(&Hb[0][hswz(ln15, kc * 64 + lg * 16)]);

    for (int nt = wv; nt < 49; nt += 4) {
        int n = nt * 16 + ln15;
        float bo = b_ho[n];
        f32x4 acc = {bo, bo, bo, bo};
        #pragma unroll
        for (int kc = 0; kc < 4; ++kc) {
            const float* p = W_ho + n * HID + kc * 32 + lg * 8;
            bf16x8 bfrag;
            #pragma unroll
            for (int e = 0; e < 8; ++e) bfrag[e] = f2bf(p[e]);
            acc = __builtin_amdgcn_mfma_f32_16x16x32_bf16(af[kc], bfrag, acc, 0, 0, 0);
        }
        #pragma unroll
        for (int r = 0; r < 4; ++r) {
            int row = lg * 4 + r;
            out[(size_t)(b0 + row) * OUT_D + n] = acc[r];
        }
    }
}

extern "C" void kernel_launch(void* const* d_in, const int* in_sizes, int n_in,
                              void* d_out, int out_size, void* d_ws, size_t ws_size,
                              hipStream_t stream) {
    const float* x    = (const float*)d_in[0];
    const float* h0   = (const float*)d_in[1];
    const float* W_ih = (const float*)d_in[2];
    const float* b_ih = (const float*)d_in[3];
    const float* W_hh = (const float*)d_in[4];
    const float* b_hh = (const float*)d_in[5];
    const float* W_ho = (const float*)d_in[6];
    const float* b_ho = (const float*)d_in[7];
    rnn_fused<<<B_TOT / BM, 256, 0, stream>>>(x, h0, W_ih, b_ih, W_hh, b_hh,
                                              W_ho, b_ho, (float*)d_out);
}

// Round 7
// 105.203 us; speedup vs baseline: 1.1550x; 1.0209x over previous
//
#include <hip/hip_runtime.h>
#include <hip/hip_bf16.h>

#define B_TOT   4096
#define T_STEPS 256
#define IN_D    28
#define HID     128
#define OUT_D   784
#define BM      16

typedef __bf16 bf16x8 __attribute__((ext_vector_type(8)));
typedef __bf16 bf16x4 __attribute__((ext_vector_type(4)));
typedef float  f32x4  __attribute__((ext_vector_type(4)));
typedef float  f32x2  __attribute__((ext_vector_type(2)));

__device__ __forceinline__ float bf2f(__bf16 b) {
    unsigned short s = __builtin_bit_cast(unsigned short, b);
    unsigned int u = ((unsigned int)s) << 16;
    return __builtin_bit_cast(float, u);
}
__device__ __forceinline__ unsigned short f2bfbits(float f) {
    unsigned int u = __builtin_bit_cast(unsigned int, f);
    u += 0x7fffu + ((u >> 16) & 1u);   // RNE (finite values)
    return (unsigned short)(u >> 16);
}

// H LDS layout: [16 rows b][128 bf16 n] = 256 B/row, XOR-swizzled so the
// stride-256B b128 reads spread across banks (2-way = free, m136).
__device__ __forceinline__ int hswz(int row, int byteInRow) {
    return row * 256 + (byteInRow ^ ((row & 7) << 4));
}

__global__ __launch_bounds__(256) void rnn_fused(
    const float* __restrict__ x,     // [B,T,IN] f32
    const float* __restrict__ h0,    // [B,HID] f32
    const float* __restrict__ W_ih,  // [HID,IN] f32
    const float* __restrict__ b_ih,  // [HID] f32
    const float* __restrict__ W_hh,  // [HID,HID] f32
    const float* __restrict__ b_hh,  // [HID] f32
    const float* __restrict__ W_ho,  // [OUT_D,HID] f32
    const float* __restrict__ b_ho,  // [OUT_D] f32
    float* __restrict__ out)         // [B*OUT_D] f32, then [B*HID] f32
{
    __shared__ __align__(16) unsigned char Hb[2][BM * 256]; // h (bf16) double buffer
    __shared__ __align__(16) unsigned char Xb[2][BM * 80];  // x_t (bf16) double buffer, [16][40]

    const int tid  = threadIdx.x;
    const int lane = tid & 63;
    const int wv   = tid >> 6;       // wave 0..3
    const int ln15 = lane & 15;
    const int lg   = lane >> 4;      // k-group 0..3
    const int b0   = blockIdx.x * BM;

    // ---- Weight fragments (f32 -> bf16), register-resident, used as the
    // MFMA *A* operand: A[m = n_out][k], lane: m = nt+ln15, k = 8*lg+e.
    const int nt0 = wv * 32;         // this wave owns hidden cols [nt0, nt0+32)
    bf16x8 bw[2][4];
    #pragma unroll
    for (int ti = 0; ti < 2; ++ti) {
        int n = nt0 + ti * 16 + ln15;
        #pragma unroll
        for (int kc = 0; kc < 4; ++kc) {
            const float* p = W_hh + n * HID + kc * 32 + lg * 8;
            bf16x8 v;
            #pragma unroll
            for (int e = 0; e < 8; ++e) v[e] = (__bf16)p[e];
            bw[ti][kc] = v;
        }
    }
    const __bf16 bzero = (__bf16)0.0f;
    bf16x8 bxf[2];
    #pragma unroll
    for (int ti = 0; ti < 2; ++ti) {
        int n = nt0 + ti * 16 + ln15;
        bf16x8 v;
        #pragma unroll
        for (int e = 0; e < 8; ++e) {
            int k = lg * 8 + e;
            v[e] = (k < IN_D) ? (__bf16)W_ih[n * IN_D + k] : bzero;  // zero-pad K 28->32
        }
        bxf[ti] = v;
    }
    // bias per lane: D row = n_out = nt0 + ti*16 + 4*lg + r  (4 consecutive)
    f32x4 bias4[2];
    #pragma unroll
    for (int ti = 0; ti < 2; ++ti) {
        int n = nt0 + ti * 16 + 4 * lg;
        f32x4 bi = *(const f32x4*)(b_ih + n);
        f32x4 bh = *(const f32x4*)(b_hh + n);
        bias4[ti] = bi + bh;
    }

    // ---- stage initial hidden into Hb[0] (f32 -> bf16)
    {
        int row = tid >> 4, cg = tid & 15;
        const float* p = h0 + (size_t)(b0 + row) * HID + cg * 8;
        bf16x8 hv;
        #pragma unroll
        for (int e = 0; e < 8; ++e) hv[e] = (__bf16)p[e];
        *(bf16x8*)(&Hb[0][hswz(row, cg * 16)]) = hv;
    }
    // ---- zero the k=28..31 pad of both X buffers (staging never touches it)
    if (tid < 64) {
        int bufi = tid >> 5, idx = tid & 31, row = idx >> 1, half = idx & 1;
        *(unsigned int*)(&Xb[bufi][row * 80 + 56 + half * 4]) = 0u;
    }
    // ---- stage x_0: 16 rows x 14 float-pairs, convert to packed bf16x2
    const int xrow = tid / 14, xpair = tid % 14;
    const bool xthr = (tid < 224);
    const float* xbase = x + (size_t)(b0 + xrow) * T_STEPS * IN_D + xpair * 2;
    if (xthr) {
        f32x2 v = *(const f32x2*)(xbase + 0 * IN_D);
        unsigned int pk = ((unsigned int)f2bfbits(v[1]) << 16) | f2bfbits(v[0]);
        *(unsigned int*)(&Xb[0][xrow * 80 + xpair * 4]) = pk;
    }
    // ---- deep x prefetch ring: p0..p3 hold x_{t+1}..x_{t+4}
    f32x2 p0 = {0.f, 0.f}, p1 = p0, p2 = p0, p3 = p0;
    if (xthr) {
        p0 = *(const f32x2*)(xbase + 1 * IN_D);
        p1 = *(const f32x2*)(xbase + 2 * IN_D);
        p2 = *(const f32x2*)(xbase + 3 * IN_D);
        p3 = *(const f32x2*)(xbase + 4 * IN_D);
    }
    __syncthreads();

    // ================= recurrence: 256 steps, 1 barrier/step =================
    // Transposed MFMA: D[n_out][batch] = W * h^T.  A = weight frag (regs),
    // B = h frag (b128 from LDS).  Lane holds batch=ln15, n_out = nt+4lg+r
    // -> 4 consecutive n_out pack into ONE ds_write_b64.
#define STEP(T, P)                                                              \
    {                                                                           \
        const int rb = (T) & 1;                                                 \
        bf16x8 ax  = *(const bf16x8*)(&Xb[rb][ln15 * 80 + lg * 16]);            \
        bf16x8 ah0 = *(const bf16x8*)(&Hb[rb][hswz(ln15,   0 + lg * 16)]);      \
        bf16x8 ah1 = *(const bf16x8*)(&Hb[rb][hswz(ln15,  64 + lg * 16)]);      \
        bf16x8 ah2 = *(const bf16x8*)(&Hb[rb][hswz(ln15, 128 + lg * 16)]);      \
        bf16x8 ah3 = *(const bf16x8*)(&Hb[rb][hswz(ln15, 192 + lg * 16)]);      \
        if (((T) + 1 < T_STEPS) && xthr) {                                      \
            unsigned int pk = ((unsigned int)f2bfbits(P[1]) << 16) | f2bfbits(P[0]); \
            *(unsigned int*)(&Xb[rb ^ 1][xrow * 80 + xpair * 4]) = pk;          \
        }                                                                       \
        if (((T) + 5 < T_STEPS) && xthr)                                        \
            P = *(const f32x2*)(xbase + (size_t)((T) + 5) * IN_D);              \
        f32x4 a0 = bias4[0], a1 = bias4[1];                                     \
        f32x4 c0 = {0.f, 0.f, 0.f, 0.f}, c1 = c0;                               \
        a0 = __builtin_amdgcn_mfma_f32_16x16x32_bf16(bxf[0],   ax,  a0, 0, 0, 0); \
        a1 = __builtin_amdgcn_mfma_f32_16x16x32_bf16(bxf[1],   ax,  a1, 0, 0, 0); \
        a0 = __builtin_amdgcn_mfma_f32_16x16x32_bf16(bw[0][0], ah0, a0, 0, 0, 0); \
        a1 = __builtin_amdgcn_mfma_f32_16x16x32_bf16(bw[1][0], ah0, a1, 0, 0, 0); \
        c0 = __builtin_amdgcn_mfma_f32_16x16x32_bf16(bw[0][1], ah1, c0, 0, 0, 0); \
        c1 = __builtin_amdgcn_mfma_f32_16x16x32_bf16(bw[1][1], ah1, c1, 0, 0, 0); \
        a0 = __builtin_amdgcn_mfma_f32_16x16x32_bf16(bw[0][2], ah2, a0, 0, 0, 0); \
        a1 = __builtin_amdgcn_mfma_f32_16x16x32_bf16(bw[1][2], ah2, a1, 0, 0, 0); \
        c0 = __builtin_amdgcn_mfma_f32_16x16x32_bf16(bw[0][3], ah3, c0, 0, 0, 0); \
        c1 = __builtin_amdgcn_mfma_f32_16x16x32_bf16(bw[1][3], ah3, c1, 0, 0, 0); \
        _Pragma("unroll")                                                       \
        for (int ti = 0; ti < 2; ++ti) {                                        \
            f32x4 s = ti ? (a1 + c1) : (a0 + c0);                               \
            bf16x4 w;                                                           \
            _Pragma("unroll")                                                   \
            for (int r = 0; r < 4; ++r) {                                       \
                float v = s[r];                                                 \
                w[r] = (__bf16)(v > 0.f ? v : 0.f);                             \
            }                                                                   \
            *(bf16x4*)(&Hb[rb ^ 1][hswz(ln15, nt0 * 2 + ti * 32 + lg * 8)]) = w; \
        }                                                                       \
        __syncthreads();                                                        \
    }

    for (int t = 0; t < T_STEPS; t += 4) {
        STEP(t + 0, p0)
        STEP(t + 1, p1)
        STEP(t + 2, p2)
        STEP(t + 3, p3)
    }
#undef STEP
    // after t=255 (rb=1) the final h sits in Hb[0]

    // ================= epilogue =================
    // h_final -> d_out second segment (f32)
    {
        int row = tid >> 4, cg = tid & 15;
        bf16x8 hv = *(const bf16x8*)(&Hb[0][hswz(row, cg * 16)]);
        float* po = out + (size_t)B_TOT * OUT_D + (size_t)(b0 + row) * HID + cg * 8;
        #pragma unroll
        for (int e = 0; e < 8; ++e) po[e] = bf2f(hv[e]);
    }
    // projection (transposed form): D[o][batch], A = W_ho frag, B = h frag.
    bf16x8 af[4];
    #pragma unroll
    for (int kc = 0; kc < 4; ++kc)
        af[kc] = *(const bf16x8*)(&Hb[0][hswz(ln15, kc * 64 + lg * 16)]);

    for (int nt = wv; nt < 49; nt += 4) {
        f32x4 acc = *(const f32x4*)(b_ho + nt * 16 + 4 * lg);
        #pragma unroll
        for (int kc = 0; kc < 4; ++kc) {
            const float* p = W_ho + (nt * 16 + ln15) * HID + kc * 32 + lg * 8;
            bf16x8 bfrag;
            #pragma unroll
            for (int e = 0; e < 8; ++e) bfrag[e] = (__bf16)p[e];
            acc = __builtin_amdgcn_mfma_f32_16x16x32_bf16(bfrag, af[kc], acc, 0, 0, 0);
        }
        // lane holds batch=ln15, o = nt*16 + 4lg + r -> one dwordx4 store
        *(f32x4*)(out + (size_t)(b0 + ln15) * OUT_D + nt * 16 + 4 * lg) = acc;
    }
}

extern "C" void kernel_launch(void* const* d_in, const int* in_sizes, int n_in,
                              void* d_out, int out_size, void* d_ws, size_t ws_size,
                              hipStream_t stream) {
    const float* x    = (const float*)d_in[0];
    const float* h0   = (const float*)d_in[1];
    const float* W_ih = (const float*)d_in[2];
    const float* b_ih = (const float*)d_in[3];
    const float* W_hh = (const float*)d_in[4];
    const float* b_hh = (const float*)d_in[5];
    const float* W_ho = (const float*)d_in[6];
    const float* b_ho = (const float*)d_in[7];
    rnn_fused<<<B_TOT / BM, 256, 0, stream>>>(x, h0, W_ih, b_ih, W_hh, b_hh,
                                              W_ho, b_ho, (float*)d_out);
}